// Round 7
// baseline (183.429 us; speedup 1.0000x reference)
//
#include <hip/hip_runtime.h>
#include <hip/hip_fp16.h>

// GCN 2-layer + classifier, fp32 math, fp16 message buffers.
// R15: WAVE-PER-NODE aggregation. Lane=(edge-slot k, feature-octet f).
//      Per chunk: 1 col load (8 u16) + 1 inv gather + 1 uint4 feature gather
//      for 8 edges x 64 features. chunks/wave = ceil(deg/8) ~2.3 (max-of-8
//      skew structurally gone, no perm). Per-thread state ~a[8]+uint4 ->
//      VGPR ~50 (vs 132) -> 8 waves/SIMD occupancy step (<=64 VGPR).
//      Cross-slot reduce: 3x shfl_xor (8/16/32). Wave loops 8 nodes
//      (block=512thr=64 nodes) so phase B keeps R2's efficient
//      (node x col-octet, o[8]-in-reg) mapping. rbuf rows padded to 68
//      floats (16B-aligned b128 rows, 2-way bank alias = free).
// R14 perm / R13 caps / R12 LDS-atomics / R11 pipeline all REVERTED
//      (measured: 163 / 174 / 816 / 190 vs R2's 156.8).
// R9/R10 kept: gemm1 fused into hist kernel; P1 UNSCALED h=X@W1; src-side
//      norm as gathered wk=inv[src] in aggF1; P2 pre-scaled by inv.
// CSR-by-dst rebuilt per launch via radix partition, ZERO global atomics.
// Requires n < 65536 (u16 col). Here n=50000, E=800000.

#define FDIM 64
#define NCLS 16
#define TILE 2048

// ---- partition pass 1: per-(tile,bucket) histogram + fused layer-1 GEMM ----
__global__ __launch_bounds__(256) void k_histgemm(const int* __restrict__ dst, int E,
                                                  int* __restrict__ H, int nblk,
                                                  const float* __restrict__ X,
                                                  const float* __restrict__ W,
                                                  __half* __restrict__ Yh, int n) {
    __shared__ float Ws[FDIM * FDIM];
    __shared__ int h[256];
    int t = threadIdx.x, blk = blockIdx.x;
    if (blk < nblk) {
        h[t] = 0;
        __syncthreads();
        int i0 = blk * TILE;
#pragma unroll
        for (int k = 0; k < TILE / 256; ++k) {
            int i = i0 + k * 256 + t;
            if (i < E) atomicAdd(&h[dst[i] >> 8], 1);
        }
        __syncthreads();
        H[blk * 256 + t] = h[t];   // coalesced
    } else {
        for (int i = t; i < FDIM * FDIM; i += 256) Ws[i] = W[i];
        __syncthreads();
        int idx = (blk - nblk) * 256 + t;
        int row = idx >> 2;
        int cg = (idx & 3) * 16;
        if (row >= n) return;
        const float4* xr = (const float4*)(X + (size_t)row * FDIM);
        float4 xv[16];
#pragma unroll
        for (int i = 0; i < 16; ++i) xv[i] = xr[i];
        float acc[16];
#pragma unroll
        for (int c = 0; c < 16; ++c) acc[c] = 0.f;
#pragma unroll
        for (int i = 0; i < 16; ++i) {
            float xs[4] = {xv[i].x, xv[i].y, xv[i].z, xv[i].w};
#pragma unroll
            for (int j = 0; j < 4; ++j) {
                float xk = xs[j];
                const float* wr = &Ws[(i * 4 + j) * FDIM + cg];
#pragma unroll
                for (int c = 0; c < 16; ++c) acc[c] += xk * wr[c];
            }
        }
        unsigned u[8];
#pragma unroll
        for (int i = 0; i < 8; ++i) {
            __half2 hp = __floats2half2_rn(acc[2 * i], acc[2 * i + 1]);
            u[i] = *(unsigned*)&hp;
        }
        uint4* yo = (uint4*)(Yh + (size_t)row * FDIM + cg);
        yo[0] = make_uint4(u[0], u[1], u[2], u[3]);
        yo[1] = make_uint4(u[4], u[5], u[6], u[7]);
    }
}

// ---- partition pass 2: per-bucket exclusive scan across tiles ----
__global__ __launch_bounds__(512) void k_scanH(int* __restrict__ H, int nblk, int* __restrict__ btot) {
    __shared__ int s[512];
    int t = threadIdx.x, b = blockIdx.x;
    int v = (t < nblk) ? H[t * 256 + b] : 0;
    s[t] = v;
    __syncthreads();
    for (int off = 1; off < 512; off <<= 1) {
        int add = (t >= off) ? s[t - off] : 0;
        __syncthreads();
        s[t] += add;
        __syncthreads();
    }
    if (t < nblk) H[t * 256 + b] = s[t] - v;  // exclusive within bucket
    if (t == 511) btot[b] = s[511];
}

// ---- partition pass 3: scatter packed records into bucket regions ----
__global__ __launch_bounds__(256) void k_scatA(const int* __restrict__ src, const int* __restrict__ dst,
                                               int E, const int* __restrict__ H,
                                               const int* __restrict__ btot, int nb,
                                               unsigned* __restrict__ tmp) {
    __shared__ int s[256];
    __shared__ int Hb[256];
    __shared__ int c2[256];
    int t = threadIdx.x, blk = blockIdx.x;
    int v = (t < nb) ? btot[t] : 0;
    s[t] = v;
    __syncthreads();
    for (int off = 1; off < 256; off <<= 1) {
        int add = (t >= off) ? s[t - off] : 0;
        __syncthreads();
        s[t] += add;
        __syncthreads();
    }
    Hb[t] = (s[t] - v) + H[blk * 256 + t];   // bucket base + tile offset
    c2[t] = 0;
    __syncthreads();
    int i0 = blk * TILE;
#pragma unroll
    for (int k = 0; k < TILE / 256; ++k) {
        int i = i0 + k * 256 + t;
        if (i < E) {
            int sv = src[i], d = dst[i];
            int b = d >> 8;
            unsigned rec = ((unsigned)(d & 255) << 16) | (unsigned)sv;
            int pos = Hb[b] + atomicAdd(&c2[b], 1);
            tmp[pos] = rec;
        }
    }
}

// ---- per-bucket CSR finalize: row_ptr, inv, coalesced u16 col ----
#define COLCAP 8192
__global__ __launch_bounds__(256) void k_binB(const unsigned* __restrict__ tmp,
                                              const int* __restrict__ btot, int nb,
                                              int n, int E, int* __restrict__ row_ptr,
                                              float* __restrict__ inv,
                                              unsigned short* __restrict__ col) {
    __shared__ int dcnt[256], s[256], cur[256];
    __shared__ unsigned short colbuf[COLCAP];
    int t = threadIdx.x, b = blockIdx.x;
    int v = (t < nb) ? btot[t] : 0;
    s[t] = v;
    __syncthreads();
    for (int off = 1; off < 256; off <<= 1) {
        int add = (t >= off) ? s[t - off] : 0;
        __syncthreads();
        s[t] += add;
        __syncthreads();
    }
    __shared__ int baseS;
    if (t == b) baseS = s[t] - v;
    dcnt[t] = 0;
    __syncthreads();
    int base = baseS;
    int cntE = btot[b];
    int node0 = b << 8;
    int nn = min(256, n - node0);
    for (int i = t; i < cntE; i += 256) atomicAdd(&dcnt[tmp[base + i] >> 16], 1);
    __syncthreads();
    int deg = dcnt[t];
    s[t] = deg;
    __syncthreads();
    for (int off = 1; off < 256; off <<= 1) {
        int add = (t >= off) ? s[t - off] : 0;
        __syncthreads();
        s[t] += add;
        __syncthreads();
    }
    int excl = s[t] - deg;
    if (t < nn) {
        row_ptr[node0 + t] = base + excl;
        inv[node0 + t] = rsqrtf((float)(deg + 1));
    }
    if (b == 0 && t == 0) row_ptr[n] = E;
    cur[t] = excl;
    __syncthreads();
    for (int i = t; i < cntE; i += 256) {
        unsigned r = tmp[base + i];
        int pos = atomicAdd(&cur[r >> 16], 1);
        unsigned short vv = (unsigned short)(r & 0xFFFFu);
        if (pos < COLCAP) colbuf[pos] = vv;
        else col[base + pos] = vv;   // overflow fallback
    }
    __syncthreads();
    int lim = min(cntE, COLCAP);
    for (int i = t; i < lim; i += 256) col[base + i] = colbuf[i];
}

__device__ __forceinline__ void unpack8(const uint4& q, float* f) {
    float2 f0 = __half22float2(*(const __half2*)&q.x);
    float2 f1 = __half22float2(*(const __half2*)&q.y);
    float2 f2 = __half22float2(*(const __half2*)&q.z);
    float2 f3 = __half22float2(*(const __half2*)&q.w);
    f[0] = f0.x; f[1] = f0.y; f[2] = f1.x; f[3] = f1.y;
    f[4] = f2.x; f[5] = f2.y; f[6] = f3.x; f[7] = f3.y;
}

// ---- agg layer 1, WAVE-PER-NODE + fused W2 GEMM -> P2 (fp16, pre-scaled) ----
// Phase A: wave = 1 node/iter, 8 iters (block = 8 waves = 64 nodes).
//   lane=(k,f): per chunk of 8 edges: c=col[s+t*8+k] (16B/wave),
//   wk=inv[c], q=Pq[c*8+f] (128B/edge line, perfectly coalesced).
//   Reduce over k: shfl_xor 8/16/32. Epilogue on k==0 lanes ->
//   rbuf[node][f*8..] = relu(iv*(sum + iv*self) + b1).
// Phase B: 512 thr = 64 nodes x 8 col-octets, o[8] in regs,
//   P2[node] = fp16(iv * (r @ W2)).
__global__ __launch_bounds__(512) void k_aggF1(const __half* __restrict__ Ph, const float* __restrict__ inv,
                                               const int* __restrict__ row_ptr,
                                               const unsigned short* __restrict__ col,
                                               const float* __restrict__ bias,
                                               const float* __restrict__ W2,
                                               __half* __restrict__ P2, int n) {
    __shared__ float W2s[FDIM * FDIM];
    __shared__ float rbuf[64][68];   // row stride 68 floats = 272B (16B-aligned)
    int t = threadIdx.x;
    for (int i = t; i < FDIM * FDIM; i += 512) W2s[i] = W2[i];
    int wid = t >> 6;
    int lane = t & 63;
    int k = lane >> 3;   // edge slot
    int f = lane & 7;    // feature octet
    int node0 = blockIdx.x * 64;
    const uint4* Pq = (const uint4*)Ph;
    for (int it = 0; it < 8; ++it) {
        int node = node0 + wid * 8 + it;
        bool alive = node < n;
        int nodeC = alive ? node : (n - 1);
        int s = row_ptr[nodeC];
        int e = alive ? row_ptr[nodeC + 1] : s;
        float a[8];
#pragma unroll
        for (int i = 0; i < 8; ++i) a[i] = 0.f;
        for (int j = s + k; j < e; j += 8) {
            int c = col[j];
            float wk = inv[c];
            uint4 q = Pq[(size_t)c * 8 + f];
            float fv[8];
            unpack8(q, fv);
#pragma unroll
            for (int i = 0; i < 8; ++i) a[i] = fmaf(wk, fv[i], a[i]);
        }
#pragma unroll
        for (int m = 8; m < 64; m <<= 1) {
#pragma unroll
            for (int i = 0; i < 8; ++i) a[i] += __shfl_xor(a[i], m, 64);
        }
        if (k == 0) {
            float iv = inv[nodeC];
            uint4 sq = Pq[(size_t)nodeC * 8 + f];
            float sf[8];
            unpack8(sq, sf);
            float4 bb0 = ((const float4*)bias)[f * 2];
            float4 bb1 = ((const float4*)bias)[f * 2 + 1];
            float4 r0, r1;
            r0.x = fmaxf(fmaf(iv, a[0] + iv * sf[0], bb0.x), 0.f);
            r0.y = fmaxf(fmaf(iv, a[1] + iv * sf[1], bb0.y), 0.f);
            r0.z = fmaxf(fmaf(iv, a[2] + iv * sf[2], bb0.z), 0.f);
            r0.w = fmaxf(fmaf(iv, a[3] + iv * sf[3], bb0.w), 0.f);
            r1.x = fmaxf(fmaf(iv, a[4] + iv * sf[4], bb1.x), 0.f);
            r1.y = fmaxf(fmaf(iv, a[5] + iv * sf[5], bb1.y), 0.f);
            r1.z = fmaxf(fmaf(iv, a[6] + iv * sf[6], bb1.z), 0.f);
            r1.w = fmaxf(fmaf(iv, a[7] + iv * sf[7], bb1.w), 0.f);
            float4* rw = (float4*)(&rbuf[wid * 8 + it][f * 8]);
            rw[0] = r0;
            rw[1] = r1;
        }
    }
    __syncthreads();
    // Phase B: 512 threads = 64 nodes x 8 col-octets
    int nl2 = t >> 3;
    int cg = t & 7;
    int node2 = node0 + nl2;
    const float* rr = rbuf[nl2];
    float o[8];
#pragma unroll
    for (int i = 0; i < 8; ++i) o[i] = 0.f;
#pragma unroll
    for (int i = 0; i < FDIM; ++i) {
        float xk = rr[i];
        const float* wv = &W2s[i * FDIM + cg * 8];
#pragma unroll
        for (int c = 0; c < 8; ++c) o[c] = fmaf(xk, wv[c], o[c]);
    }
    if (node2 < n) {
        float iv2 = inv[node2];
        unsigned u[4];
#pragma unroll
        for (int i = 0; i < 4; ++i) {
            __half2 hp = __floats2half2_rn(o[2 * i] * iv2, o[2 * i + 1] * iv2);
            u[i] = *(unsigned*)&hp;
        }
        ((uint4*)P2)[(size_t)node2 * 8 + cg] = make_uint4(u[0], u[1], u[2], u[3]);
    }
}

// ---- agg layer 2, WAVE-PER-NODE + fused classifier (P2 pre-scaled) ----
__global__ __launch_bounds__(512) void k_aggF2(const __half* __restrict__ Ph, const float* __restrict__ inv,
                                               const int* __restrict__ row_ptr,
                                               const unsigned short* __restrict__ col,
                                               const float* __restrict__ bias,
                                               const float* __restrict__ Wc, const float* __restrict__ bc,
                                               float* __restrict__ out, int n) {
    __shared__ float WcT[NCLS * FDIM];   // transposed: WcT[c*64+f]
    __shared__ float rbuf[64][68];
    int t = threadIdx.x;
    for (int i = t; i < FDIM * NCLS; i += 512) {
        int c = i & 15, ff = i >> 4;
        WcT[c * FDIM + ff] = Wc[i];
    }
    int wid = t >> 6;
    int lane = t & 63;
    int k = lane >> 3;
    int f = lane & 7;
    int node0 = blockIdx.x * 64;
    const uint4* Pq = (const uint4*)Ph;
    for (int it = 0; it < 8; ++it) {
        int node = node0 + wid * 8 + it;
        bool alive = node < n;
        int nodeC = alive ? node : (n - 1);
        int s = row_ptr[nodeC];
        int e = alive ? row_ptr[nodeC + 1] : s;
        float a[8];
#pragma unroll
        for (int i = 0; i < 8; ++i) a[i] = 0.f;
        for (int j = s + k; j < e; j += 8) {
            int c = col[j];
            uint4 q = Pq[(size_t)c * 8 + f];
            float fv[8];
            unpack8(q, fv);
#pragma unroll
            for (int i = 0; i < 8; ++i) a[i] += fv[i];
        }
#pragma unroll
        for (int m = 8; m < 64; m <<= 1) {
#pragma unroll
            for (int i = 0; i < 8; ++i) a[i] += __shfl_xor(a[i], m, 64);
        }
        if (k == 0) {
            float iv = inv[nodeC];
            uint4 sq = Pq[(size_t)nodeC * 8 + f];
            float sf[8];
            unpack8(sq, sf);
            float4 bb0 = ((const float4*)bias)[f * 2];
            float4 bb1 = ((const float4*)bias)[f * 2 + 1];
            float4 r0, r1;
            r0.x = fmaxf(fmaf(iv, a[0] + sf[0], bb0.x), 0.f);
            r0.y = fmaxf(fmaf(iv, a[1] + sf[1], bb0.y), 0.f);
            r0.z = fmaxf(fmaf(iv, a[2] + sf[2], bb0.z), 0.f);
            r0.w = fmaxf(fmaf(iv, a[3] + sf[3], bb0.w), 0.f);
            r1.x = fmaxf(fmaf(iv, a[4] + sf[4], bb1.x), 0.f);
            r1.y = fmaxf(fmaf(iv, a[5] + sf[5], bb1.y), 0.f);
            r1.z = fmaxf(fmaf(iv, a[6] + sf[6], bb1.z), 0.f);
            r1.w = fmaxf(fmaf(iv, a[7] + sf[7], bb1.w), 0.f);
            float4* rw = (float4*)(&rbuf[wid * 8 + it][f * 8]);
            rw[0] = r0;
            rw[1] = r1;
        }
    }
    __syncthreads();
    // classifier: 512 threads = 64 nodes x 8 octets; reduce over octets via shfl
    int nl = t >> 3;
    int fl = t & 7;
    int node2 = node0 + nl;
    const float* rr = rbuf[nl];
    float r[8];
#pragma unroll
    for (int i = 0; i < 8; ++i) r[i] = rr[fl * 8 + i];
    float part[NCLS];
#pragma unroll
    for (int c = 0; c < NCLS; ++c) {
        float4 wv0 = ((const float4*)(WcT + c * FDIM))[fl * 2];
        float4 wv1 = ((const float4*)(WcT + c * FDIM))[fl * 2 + 1];
        part[c] = r[0] * wv0.x;
        part[c] = fmaf(r[1], wv0.y, part[c]);
        part[c] = fmaf(r[2], wv0.z, part[c]);
        part[c] = fmaf(r[3], wv0.w, part[c]);
        part[c] = fmaf(r[4], wv1.x, part[c]);
        part[c] = fmaf(r[5], wv1.y, part[c]);
        part[c] = fmaf(r[6], wv1.z, part[c]);
        part[c] = fmaf(r[7], wv1.w, part[c]);
    }
#pragma unroll
    for (int m = 1; m < 8; m <<= 1) {
#pragma unroll
        for (int c = 0; c < NCLS; ++c) part[c] += __shfl_xor(part[c], m, 64);
    }
    if (node2 < n && fl < 4) {
        float4 bb2 = ((const float4*)bc)[fl];
        float4 o = make_float4(part[fl * 4 + 0] + bb2.x, part[fl * 4 + 1] + bb2.y,
                               part[fl * 4 + 2] + bb2.z, part[fl * 4 + 3] + bb2.w);
        ((float4*)out)[(size_t)node2 * 4 + fl] = o;
    }
}

static inline size_t align256(size_t x) { return (x + 255) & ~(size_t)255; }

extern "C" void kernel_launch(void* const* d_in, const int* in_sizes, int n_in,
                              void* d_out, int out_size, void* d_ws, size_t ws_size,
                              hipStream_t stream) {
    const float* x  = (const float*)d_in[0];
    const int*   ei = (const int*)d_in[1];
    const float* W1 = (const float*)d_in[2];
    const float* b1 = (const float*)d_in[3];
    const float* W2 = (const float*)d_in[4];
    const float* b2 = (const float*)d_in[5];
    const float* Wc = (const float*)d_in[6];
    const float* bc = (const float*)d_in[7];
    float* out = (float*)d_out;

    const int n = in_sizes[0] / FDIM;   // 50000
    const int E = in_sizes[1] / 2;      // 800000
    const int* src = ei;
    const int* dst = ei + E;

    const int nb = (n + 255) >> 8;            // 196 buckets
    const int nblk = (E + TILE - 1) / TILE;   // 391 tiles

    // workspace carve-up
    char* w = (char*)d_ws;
    size_t off = 0;
    int* H = (int*)(w + off);        off = align256(off + (size_t)nblk * 256 * 4);
    int* btot = (int*)(w + off);     off = align256(off + 256 * 4);
    int* row_ptr = (int*)(w + off);  off = align256(off + (size_t)(n + 1) * 4);
    float* inv = (float*)(w + off);  off = align256(off + (size_t)n * 4);
    unsigned* tmp = (unsigned*)(w + off);             off = align256(off + (size_t)E * 4);
    unsigned short* col = (unsigned short*)(w + off); off = align256(off + (size_t)(E + 8) * 2);
    __half* P1 = (__half*)(w + off); off = align256(off + (size_t)n * FDIM * 2);
    __half* P2 = (__half*)(w + off); off = align256(off + (size_t)n * FDIM * 2);
    (void)ws_size;

    const int nbG = (n * 4 + 255) / 256;
    const int nbA = (n + 63) / 64;     // 64 nodes per block (8 waves x 8 nodes)

    // CSR build + fused layer-1 GEMM riding along
    k_histgemm<<<nblk + nbG, 256, 0, stream>>>(dst, E, H, nblk, x, W1, P1, n);
    k_scanH<<<nb, 512, 0, stream>>>(H, nblk, btot);
    k_scatA<<<nblk, 256, 0, stream>>>(src, dst, E, H, btot, nb, tmp);
    k_binB<<<nb, 256, 0, stream>>>(tmp, btot, nb, n, E, row_ptr, inv, col);

    // wave-per-node agg layer 1 (inv[src]-weighted) + fused W2 GEMM -> P2
    k_aggF1<<<nbA, 512, 0, stream>>>(P1, inv, row_ptr, col, b1, W2, P2, n);
    // wave-per-node agg layer 2 + fused classifier
    k_aggF2<<<nbA, 512, 0, stream>>>(P2, inv, row_ptr, col, b2, Wc, bc, out, n);
}

// Round 8
// 156.522 us; speedup vs baseline: 1.1719x; 1.1719x over previous
//
#include <hip/hip_runtime.h>
#include <hip/hip_fp16.h>

// GCN 2-layer + classifier, fp32 math, fp16 message buffers.
// R16: R2 shape (best measured: 156.8us) + PADDED-CSR register diet.
//      Six structural rewrites (R11-R15) all lost to R2's plain loop; its
//      limiter is residency: VGPR=132 -> 2 waves/SIMD (steps at 64/128/256).
//      Fix: binB pads every row to a multiple of 8 edges with SENTINEL
//      entries (node n: inv[n]=0, P1/P2 row n zeroed); packed
//      row_ptr = start | nch<<22 (padded bucket bases align8(base)+b*2056).
//      Aggs then: 8 cols = ONE uint4 load (16B-aligned rows), zero per-edge
//      compares/masks (aggF2 loses wk[] entirely). VMEM/chunk 24->17 (F1),
//      24->9 (F2); VGPR ~95-115 -> __launch_bounds__(256,4) = 4 waves/SIMD
//      without spill pressure (R5 lesson: 6 waves/85 VGPR spilled).
//      Arithmetic BIT-IDENTICAL to R2 (sentinel adds fma(0,0,a)).
// R10: 8 lanes/node * uint4 feature gathers (0.375 VMEM/edge) - kept.
// R9: gemm1 fused into hist kernel; P1 UNSCALED h=X@W1; src-side norm as
//     gathered wk=inv[src] in aggF1; P2 pre-scaled by inv - kept.
// CSR-by-dst rebuilt per launch via radix partition, ZERO global atomics.
// Requires n < 65535 (u16 col + sentinel n). Here n=50000, E=800000.

#define FDIM 64
#define NCLS 16
#define TILE 2048

// ---- partition pass 1: per-(tile,bucket) histogram + fused layer-1 GEMM ----
__global__ __launch_bounds__(256) void k_histgemm(const int* __restrict__ dst, int E,
                                                  int* __restrict__ H, int nblk,
                                                  const float* __restrict__ X,
                                                  const float* __restrict__ W,
                                                  __half* __restrict__ Yh, int n) {
    __shared__ float Ws[FDIM * FDIM];
    __shared__ int h[256];
    int t = threadIdx.x, blk = blockIdx.x;
    if (blk < nblk) {
        h[t] = 0;
        __syncthreads();
        int i0 = blk * TILE;
#pragma unroll
        for (int k = 0; k < TILE / 256; ++k) {
            int i = i0 + k * 256 + t;
            if (i < E) atomicAdd(&h[dst[i] >> 8], 1);
        }
        __syncthreads();
        H[blk * 256 + t] = h[t];   // coalesced
    } else {
        for (int i = t; i < FDIM * FDIM; i += 256) Ws[i] = W[i];
        __syncthreads();
        // zero sentinel row n of P1 (padded edges gather it with weight 0)
        if (blk == nblk && t < 8)
            ((uint4*)Yh)[(size_t)n * 8 + t] = make_uint4(0, 0, 0, 0);
        int idx = (blk - nblk) * 256 + t;
        int row = idx >> 2;
        int cg = (idx & 3) * 16;
        if (row >= n) return;
        const float4* xr = (const float4*)(X + (size_t)row * FDIM);
        float4 xv[16];
#pragma unroll
        for (int i = 0; i < 16; ++i) xv[i] = xr[i];
        float acc[16];
#pragma unroll
        for (int c = 0; c < 16; ++c) acc[c] = 0.f;
#pragma unroll
        for (int i = 0; i < 16; ++i) {
            float xs[4] = {xv[i].x, xv[i].y, xv[i].z, xv[i].w};
#pragma unroll
            for (int j = 0; j < 4; ++j) {
                float xk = xs[j];
                const float* wr = &Ws[(i * 4 + j) * FDIM + cg];
#pragma unroll
                for (int c = 0; c < 16; ++c) acc[c] += xk * wr[c];
            }
        }
        unsigned u[8];
#pragma unroll
        for (int i = 0; i < 8; ++i) {
            __half2 hp = __floats2half2_rn(acc[2 * i], acc[2 * i + 1]);
            u[i] = *(unsigned*)&hp;
        }
        uint4* yo = (uint4*)(Yh + (size_t)row * FDIM + cg);
        yo[0] = make_uint4(u[0], u[1], u[2], u[3]);
        yo[1] = make_uint4(u[4], u[5], u[6], u[7]);
    }
}

// ---- partition pass 2: per-bucket exclusive scan across tiles ----
__global__ __launch_bounds__(512) void k_scanH(int* __restrict__ H, int nblk, int* __restrict__ btot) {
    __shared__ int s[512];
    int t = threadIdx.x, b = blockIdx.x;
    int v = (t < nblk) ? H[t * 256 + b] : 0;
    s[t] = v;
    __syncthreads();
    for (int off = 1; off < 512; off <<= 1) {
        int add = (t >= off) ? s[t - off] : 0;
        __syncthreads();
        s[t] += add;
        __syncthreads();
    }
    if (t < nblk) H[t * 256 + b] = s[t] - v;  // exclusive within bucket
    if (t == 511) btot[b] = s[511];
}

// ---- partition pass 3: scatter packed records into bucket regions ----
__global__ __launch_bounds__(256) void k_scatA(const int* __restrict__ src, const int* __restrict__ dst,
                                               int E, const int* __restrict__ H,
                                               const int* __restrict__ btot, int nb,
                                               unsigned* __restrict__ tmp) {
    __shared__ int s[256];
    __shared__ int Hb[256];
    __shared__ int c2[256];
    int t = threadIdx.x, blk = blockIdx.x;
    int v = (t < nb) ? btot[t] : 0;
    s[t] = v;
    __syncthreads();
    for (int off = 1; off < 256; off <<= 1) {
        int add = (t >= off) ? s[t - off] : 0;
        __syncthreads();
        s[t] += add;
        __syncthreads();
    }
    Hb[t] = (s[t] - v) + H[blk * 256 + t];   // bucket base + tile offset
    c2[t] = 0;
    __syncthreads();
    int i0 = blk * TILE;
#pragma unroll
    for (int k = 0; k < TILE / 256; ++k) {
        int i = i0 + k * 256 + t;
        if (i < E) {
            int sv = src[i], d = dst[i];
            int b = d >> 8;
            unsigned rec = ((unsigned)(d & 255) << 16) | (unsigned)sv;
            int pos = Hb[b] + atomicAdd(&c2[b], 1);
            tmp[pos] = rec;
        }
    }
}

// ---- per-bucket CSR finalize: PADDED rows, packed row_ptr, sentinel fill ----
// pbase = align8(base) + b*2056 guarantees non-overlapping padded regions
// (per-bucket padding <= 256 nodes * 7 + align slack < 2056) and 16B-aligned
// row starts (every pdeg is a multiple of 8). row_ptr[node] = start | nch<<22.
#define COLCAP 8192
__global__ __launch_bounds__(256) void k_binB(const unsigned* __restrict__ tmp,
                                              const int* __restrict__ btot, int nb,
                                              int n, int E, int* __restrict__ row_ptr,
                                              float* __restrict__ inv,
                                              unsigned short* __restrict__ col) {
    __shared__ int dcnt[256], s[256], cur[256];
    __shared__ unsigned short colbuf[COLCAP];
    __shared__ int baseS;
    int t = threadIdx.x, b = blockIdx.x;
    int v = (t < nb) ? btot[t] : 0;
    s[t] = v;
    __syncthreads();
    for (int off = 1; off < 256; off <<= 1) {
        int add = (t >= off) ? s[t - off] : 0;
        __syncthreads();
        s[t] += add;
        __syncthreads();
    }
    if (t == b) baseS = s[t] - v;
    dcnt[t] = 0;
    __syncthreads();
    int base = baseS;
    int pbase = ((base + 7) & ~7) + b * 2056;
    int cntE = btot[b];
    int node0 = b << 8;
    int nn = min(256, n - node0);
    for (int i = t; i < cntE; i += 256) atomicAdd(&dcnt[tmp[base + i] >> 16], 1);
    __syncthreads();
    int deg = dcnt[t];
    int pdeg = (deg + 7) & ~7;
    s[t] = pdeg;
    __syncthreads();
    for (int off = 1; off < 256; off <<= 1) {
        int add = (t >= off) ? s[t - off] : 0;
        __syncthreads();
        s[t] += add;
        __syncthreads();
    }
    int pexcl = s[t] - pdeg;
    int ptot = s[255];
    if (t < nn) {
        row_ptr[node0 + t] = (pbase + pexcl) | ((pdeg >> 3) << 22);
        inv[node0 + t] = rsqrtf((float)(deg + 1));
    }
    if (b == 0 && t == 0) inv[n] = 0.f;   // sentinel weight
    cur[t] = pexcl;
    __syncthreads();
    for (int i = t; i < cntE; i += 256) {
        unsigned r = tmp[base + i];
        int pos = atomicAdd(&cur[r >> 16], 1);
        unsigned short vv = (unsigned short)(r & 0xFFFFu);
        if (pos < COLCAP) colbuf[pos] = vv;
        else col[pbase + pos] = vv;   // overflow fallback
    }
    // sentinel tail fill (disjoint from scatter range -> no barrier needed)
    if (t < nn) {
        int p1 = pexcl + pdeg;
        for (int p = pexcl + deg; p < p1; ++p) {
            if (p < COLCAP) colbuf[p] = (unsigned short)n;
            else col[pbase + p] = (unsigned short)n;
        }
    }
    __syncthreads();
    int lim = min(ptot, COLCAP);
    for (int i = t; i < lim; i += 256) col[pbase + i] = colbuf[i];
}

__device__ __forceinline__ void unpack8(const uint4& q, float* f) {
    float2 f0 = __half22float2(*(const __half2*)&q.x);
    float2 f1 = __half22float2(*(const __half2*)&q.y);
    float2 f2 = __half22float2(*(const __half2*)&q.z);
    float2 f3 = __half22float2(*(const __half2*)&q.w);
    f[0] = f0.x; f[1] = f0.y; f[2] = f1.x; f[3] = f1.y;
    f[4] = f2.x; f[5] = f2.y; f[6] = f3.x; f[7] = f3.y;
}

// ---- agg layer 1 (inv[src]-weighted) + fused W2 GEMM -> P2 (fp16) ----
// Phase A: 8 nodes/wave, 8 lanes x 8 halfs (uint4); 32 nodes/block.
// Rows padded to x8 with sentinel -> chunk loop unconditional; 8 cols per
// chunk = ONE uint4 load. VMEM/chunk 17 (was 24), no per-edge compares.
// Phase B: 256 threads = 32 nodes x 8 col-octets; P2 = fp16(inv * (r @ W2)).
__global__ __launch_bounds__(256, 4) void k_aggF1(const __half* __restrict__ Ph, const float* __restrict__ inv,
                                                  const int* __restrict__ row_ptr,
                                                  const unsigned short* __restrict__ col,
                                                  const float* __restrict__ bias,
                                                  const float* __restrict__ W2,
                                                  __half* __restrict__ P2, int n) {
    __shared__ float W2s[FDIM * FDIM];
    __shared__ float rbuf[32][FDIM + 1];
    int t0 = threadIdx.x;
    for (int i = t0; i < FDIM * FDIM; i += 256) W2s[i] = W2[i];
    // zero sentinel row n of P2 for aggF2
    if (blockIdx.x == 0 && t0 < 8)
        ((uint4*)P2)[(size_t)n * 8 + t0] = make_uint4(0, 0, 0, 0);
    int lane = t0 & 63;
    int sub = lane >> 3;      // node-in-wave 0..7
    int fl = lane & 7;        // feature octet 0..7
    int wid = t0 >> 6;
    int nl = wid * 8 + sub;   // local node 0..31
    int node = blockIdx.x * 32 + nl;
    bool alive = node < n;
    int nodeC = alive ? node : (n - 1);
    float iv = inv[nodeC];
    const uint4* Pq = (const uint4*)Ph;
    uint4 selfq = Pq[(size_t)nodeC * 8 + fl];
    float a[8], f[8];
    unpack8(selfq, f);
#pragma unroll
    for (int i = 0; i < 8; ++i) a[i] = iv * f[i];   // self term: inv[d]*h[d]
    int v = row_ptr[nodeC];
    int s = v & 0x3FFFFF;
    int e = alive ? s + ((v >> 22) << 3) : s;
    for (int j = s; j < e; j += 8) {
        uint4 cv = *(const uint4*)(col + j);   // 8 u16 cols, one load
        int c[8];
        c[0] = cv.x & 0xFFFF; c[1] = cv.x >> 16;
        c[2] = cv.y & 0xFFFF; c[3] = cv.y >> 16;
        c[4] = cv.z & 0xFFFF; c[5] = cv.z >> 16;
        c[6] = cv.w & 0xFFFF; c[7] = cv.w >> 16;
        float wk[8];
#pragma unroll
        for (int k = 0; k < 8; ++k) wk[k] = inv[c[k]];   // inv[n]=0 kills pads
        uint4 q[8];
#pragma unroll
        for (int k = 0; k < 8; ++k) q[k] = Pq[(size_t)c[k] * 8 + fl];
#pragma unroll
        for (int k = 0; k < 8; ++k) {
            unpack8(q[k], f);
#pragma unroll
            for (int i = 0; i < 8; ++i) a[i] = fmaf(wk[k], f[i], a[i]);
        }
    }
    float4 bb0 = ((const float4*)bias)[fl * 2];
    float4 bb1 = ((const float4*)bias)[fl * 2 + 1];
    float bbv[8] = {bb0.x, bb0.y, bb0.z, bb0.w, bb1.x, bb1.y, bb1.z, bb1.w};
#pragma unroll
    for (int i = 0; i < 8; ++i)
        rbuf[nl][fl * 8 + i] = fmaxf(fmaf(iv, a[i], bbv[i]), 0.f);
    __syncthreads();   // covers W2s load too
    // Phase B: 256 threads = 32 nodes x 8 col-octets
    int nl2 = t0 >> 3;
    int cg = t0 & 7;
    int node2 = blockIdx.x * 32 + nl2;
    const float* rr = rbuf[nl2];
    float o[8];
#pragma unroll
    for (int i = 0; i < 8; ++i) o[i] = 0.f;
#pragma unroll
    for (int i = 0; i < FDIM; ++i) {
        float xk = rr[i];
        const float* wv = &W2s[i * FDIM + cg * 8];
#pragma unroll
        for (int c = 0; c < 8; ++c) o[c] = fmaf(xk, wv[c], o[c]);
    }
    if (node2 < n) {
        float iv2 = inv[node2];
        unsigned u[4];
#pragma unroll
        for (int i = 0; i < 4; ++i) {
            __half2 hp = __floats2half2_rn(o[2 * i] * iv2, o[2 * i + 1] * iv2);
            u[i] = *(unsigned*)&hp;
        }
        ((uint4*)P2)[(size_t)node2 * 8 + cg] = make_uint4(u[0], u[1], u[2], u[3]);
    }
}

// ---- agg layer 2 + fused classifier (P2 pre-scaled -> weight-free) ----
// Padded rows + zeroed sentinel P2 row -> unconditional adds, NO wk[] at all.
// VMEM/chunk = 9 (1 col-vec + 8 gathers).
__global__ __launch_bounds__(256, 4) void k_aggF2(const __half* __restrict__ Ph, const float* __restrict__ inv,
                                                  const int* __restrict__ row_ptr,
                                                  const unsigned short* __restrict__ col,
                                                  const float* __restrict__ bias,
                                                  const float* __restrict__ Wc, const float* __restrict__ bc,
                                                  float* __restrict__ out, int n) {
    __shared__ float WcT[NCLS * FDIM];   // transposed: WcT[c*64+f]
    int t0 = threadIdx.x;
    for (int i = t0; i < FDIM * NCLS; i += 256) {
        int c = i & 15, ff = i >> 4;
        WcT[c * FDIM + ff] = Wc[i];
    }
    __syncthreads();
    int lane = t0 & 63;
    int sub = lane >> 3;
    int fl = lane & 7;
    int wid = t0 >> 6;
    int node = blockIdx.x * 32 + wid * 8 + sub;
    bool alive = node < n;
    int nodeC = alive ? node : (n - 1);
    float iv = inv[nodeC];
    const uint4* Pq = (const uint4*)Ph;
    uint4 selfq = Pq[(size_t)nodeC * 8 + fl];
    float a[8], f[8];
    unpack8(selfq, a);
    int v = row_ptr[nodeC];
    int s = v & 0x3FFFFF;
    int e = alive ? s + ((v >> 22) << 3) : s;
    for (int j = s; j < e; j += 8) {
        uint4 cv = *(const uint4*)(col + j);
        int c[8];
        c[0] = cv.x & 0xFFFF; c[1] = cv.x >> 16;
        c[2] = cv.y & 0xFFFF; c[3] = cv.y >> 16;
        c[4] = cv.z & 0xFFFF; c[5] = cv.z >> 16;
        c[6] = cv.w & 0xFFFF; c[7] = cv.w >> 16;
        uint4 q[8];
#pragma unroll
        for (int k = 0; k < 8; ++k) q[k] = Pq[(size_t)c[k] * 8 + fl];
#pragma unroll
        for (int k = 0; k < 8; ++k) {
            unpack8(q[k], f);
#pragma unroll
            for (int i = 0; i < 8; ++i) a[i] += f[i];   // sentinel row = zeros
        }
    }
    float4 bb0 = ((const float4*)bias)[fl * 2];
    float4 bb1 = ((const float4*)bias)[fl * 2 + 1];
    float bbv[8] = {bb0.x, bb0.y, bb0.z, bb0.w, bb1.x, bb1.y, bb1.z, bb1.w};
    float r[8];
#pragma unroll
    for (int i = 0; i < 8; ++i) r[i] = fmaxf(fmaf(iv, a[i], bbv[i]), 0.f);
    float part[NCLS];
#pragma unroll
    for (int c = 0; c < NCLS; ++c) {
        float4 wv0 = ((const float4*)(WcT + c * FDIM))[fl * 2];
        float4 wv1 = ((const float4*)(WcT + c * FDIM))[fl * 2 + 1];
        part[c] = r[0] * wv0.x;
        part[c] = fmaf(r[1], wv0.y, part[c]);
        part[c] = fmaf(r[2], wv0.z, part[c]);
        part[c] = fmaf(r[3], wv0.w, part[c]);
        part[c] = fmaf(r[4], wv1.x, part[c]);
        part[c] = fmaf(r[5], wv1.y, part[c]);
        part[c] = fmaf(r[6], wv1.z, part[c]);
        part[c] = fmaf(r[7], wv1.w, part[c]);
    }
#pragma unroll
    for (int m = 1; m < 8; m <<= 1) {
#pragma unroll
        for (int c = 0; c < NCLS; ++c) part[c] += __shfl_xor(part[c], m, 64);
    }
    if (alive && fl < 4) {
        float4 bb2 = ((const float4*)bc)[fl];
        float4 o = make_float4(part[fl * 4 + 0] + bb2.x, part[fl * 4 + 1] + bb2.y,
                               part[fl * 4 + 2] + bb2.z, part[fl * 4 + 3] + bb2.w);
        ((float4*)out)[(size_t)node * 4 + fl] = o;
    }
}

static inline size_t align256(size_t x) { return (x + 255) & ~(size_t)255; }

extern "C" void kernel_launch(void* const* d_in, const int* in_sizes, int n_in,
                              void* d_out, int out_size, void* d_ws, size_t ws_size,
                              hipStream_t stream) {
    const float* x  = (const float*)d_in[0];
    const int*   ei = (const int*)d_in[1];
    const float* W1 = (const float*)d_in[2];
    const float* b1 = (const float*)d_in[3];
    const float* W2 = (const float*)d_in[4];
    const float* b2 = (const float*)d_in[5];
    const float* Wc = (const float*)d_in[6];
    const float* bc = (const float*)d_in[7];
    float* out = (float*)d_out;

    const int n = in_sizes[0] / FDIM;   // 50000
    const int E = in_sizes[1] / 2;      // 800000
    const int* src = ei;
    const int* dst = ei + E;

    const int nb = (n + 255) >> 8;            // 196 buckets
    const int nblk = (E + TILE - 1) / TILE;   // 391 tiles

    // workspace carve-up (inv/P1/P2 have +1 sentinel entry/row; col padded)
    char* w = (char*)d_ws;
    size_t off = 0;
    int* H = (int*)(w + off);        off = align256(off + (size_t)nblk * 256 * 4);
    int* btot = (int*)(w + off);     off = align256(off + 256 * 4);
    int* row_ptr = (int*)(w + off);  off = align256(off + (size_t)(n + 1) * 4);
    float* inv = (float*)(w + off);  off = align256(off + (size_t)(n + 1) * 4);
    unsigned* tmp = (unsigned*)(w + off);             off = align256(off + (size_t)E * 4);
    unsigned short* col = (unsigned short*)(w + off); off = align256(off + ((size_t)E + (size_t)nb * 2056 + 64) * 2);
    __half* P1 = (__half*)(w + off); off = align256(off + (size_t)(n + 1) * FDIM * 2);
    __half* P2 = (__half*)(w + off); off = align256(off + (size_t)(n + 1) * FDIM * 2);
    (void)ws_size;

    const int nbG = (n * 4 + 255) / 256;
    const int nbA = (n + 31) / 32;     // 32 nodes per block

    // CSR build + fused layer-1 GEMM riding along
    k_histgemm<<<nblk + nbG, 256, 0, stream>>>(dst, E, H, nblk, x, W1, P1, n);
    k_scanH<<<nb, 512, 0, stream>>>(H, nblk, btot);
    k_scatA<<<nblk, 256, 0, stream>>>(src, dst, E, H, btot, nb, tmp);
    k_binB<<<nb, 256, 0, stream>>>(tmp, btot, nb, n, E, row_ptr, inv, col);

    // layer 1 agg (inv[src]-weighted) + fused layer 2 GEMM -> P2 (pre-scaled)
    k_aggF1<<<nbA, 256, 0, stream>>>(P1, inv, row_ptr, col, b1, W2, P2, n);
    // layer 2 agg + fused classifier
    k_aggF2<<<nbA, 256, 0, stream>>>(P2, inv, row_ptr, col, b2, Wc, bc, out, n);
}

// Round 9
// 155.397 us; speedup vs baseline: 1.1804x; 1.0072x over previous
//
#include <hip/hip_runtime.h>
#include <hip/hip_fp16.h>

// GCN 2-layer + classifier, fp32 math, fp16 message buffers.
// R17: PAD-16 + 2-CHUNK STRAIGHT-LINE MLP. Ledger: issue count (R10/R16),
//      guarded pipelining (R11), LDS atomics (R12), forced TLP (R13), skew
//      (R14), wave-per-node (R15) all neutral/worse -> aggs are latency x
//      concurrency bound with per-wave MLP as the binding term. Rows padded
//      to x16 (sentinel) -> loop j+=16 issues 2 col uint4 + 16 inv + 16
//      feature gathers UNCONDITIONALLY (no R11 branch-guards -> no compiler
//      vmcnt(0) serialization), then 16 FMA groups. Outstanding/wave 17->34
//      (F1), 9->18 (F2); VGPR ~190 stays in 129-256 band -> occupancy
//      unchanged (2 waves/SIMD) -> in-flight lines/CU DOUBLES.
//      Arithmetic BIT-IDENTICAL (sentinels add fma(0,.)).
// R16: padded CSR + packed row_ptr + sentinel row n (inv[n]=0, P1/P2[n]=0).
// R10: 8 lanes/node * uint4 feature gathers. R9: gemm1 fused in histgemm;
//      P1 UNSCALED; wk=inv[src] gathered in aggF1; P2 pre-scaled by inv.
// CSR-by-dst rebuilt per launch via radix partition, ZERO global atomics.
// Requires n < 65535 (u16 col + sentinel n). Here n=50000, E=800000.

#define FDIM 64
#define NCLS 16
#define TILE 2048

// ---- partition pass 1: per-(tile,bucket) histogram + fused layer-1 GEMM ----
__global__ __launch_bounds__(256) void k_histgemm(const int* __restrict__ dst, int E,
                                                  int* __restrict__ H, int nblk,
                                                  const float* __restrict__ X,
                                                  const float* __restrict__ W,
                                                  __half* __restrict__ Yh, int n) {
    __shared__ float Ws[FDIM * FDIM];
    __shared__ int h[256];
    int t = threadIdx.x, blk = blockIdx.x;
    if (blk < nblk) {
        h[t] = 0;
        __syncthreads();
        int i0 = blk * TILE;
#pragma unroll
        for (int k = 0; k < TILE / 256; ++k) {
            int i = i0 + k * 256 + t;
            if (i < E) atomicAdd(&h[dst[i] >> 8], 1);
        }
        __syncthreads();
        H[blk * 256 + t] = h[t];   // coalesced
    } else {
        for (int i = t; i < FDIM * FDIM; i += 256) Ws[i] = W[i];
        __syncthreads();
        // zero sentinel row n of P1 (padded edges gather it with weight 0)
        if (blk == nblk && t < 8)
            ((uint4*)Yh)[(size_t)n * 8 + t] = make_uint4(0, 0, 0, 0);
        int idx = (blk - nblk) * 256 + t;
        int row = idx >> 2;
        int cg = (idx & 3) * 16;
        if (row >= n) return;
        const float4* xr = (const float4*)(X + (size_t)row * FDIM);
        float4 xv[16];
#pragma unroll
        for (int i = 0; i < 16; ++i) xv[i] = xr[i];
        float acc[16];
#pragma unroll
        for (int c = 0; c < 16; ++c) acc[c] = 0.f;
#pragma unroll
        for (int i = 0; i < 16; ++i) {
            float xs[4] = {xv[i].x, xv[i].y, xv[i].z, xv[i].w};
#pragma unroll
            for (int j = 0; j < 4; ++j) {
                float xk = xs[j];
                const float* wr = &Ws[(i * 4 + j) * FDIM + cg];
#pragma unroll
                for (int c = 0; c < 16; ++c) acc[c] += xk * wr[c];
            }
        }
        unsigned u[8];
#pragma unroll
        for (int i = 0; i < 8; ++i) {
            __half2 hp = __floats2half2_rn(acc[2 * i], acc[2 * i + 1]);
            u[i] = *(unsigned*)&hp;
        }
        uint4* yo = (uint4*)(Yh + (size_t)row * FDIM + cg);
        yo[0] = make_uint4(u[0], u[1], u[2], u[3]);
        yo[1] = make_uint4(u[4], u[5], u[6], u[7]);
    }
}

// ---- partition pass 2: per-bucket exclusive scan across tiles ----
__global__ __launch_bounds__(512) void k_scanH(int* __restrict__ H, int nblk, int* __restrict__ btot) {
    __shared__ int s[512];
    int t = threadIdx.x, b = blockIdx.x;
    int v = (t < nblk) ? H[t * 256 + b] : 0;
    s[t] = v;
    __syncthreads();
    for (int off = 1; off < 512; off <<= 1) {
        int add = (t >= off) ? s[t - off] : 0;
        __syncthreads();
        s[t] += add;
        __syncthreads();
    }
    if (t < nblk) H[t * 256 + b] = s[t] - v;  // exclusive within bucket
    if (t == 511) btot[b] = s[511];
}

// ---- partition pass 3: scatter packed records into bucket regions ----
__global__ __launch_bounds__(256) void k_scatA(const int* __restrict__ src, const int* __restrict__ dst,
                                               int E, const int* __restrict__ H,
                                               const int* __restrict__ btot, int nb,
                                               unsigned* __restrict__ tmp) {
    __shared__ int s[256];
    __shared__ int Hb[256];
    __shared__ int c2[256];
    int t = threadIdx.x, blk = blockIdx.x;
    int v = (t < nb) ? btot[t] : 0;
    s[t] = v;
    __syncthreads();
    for (int off = 1; off < 256; off <<= 1) {
        int add = (t >= off) ? s[t - off] : 0;
        __syncthreads();
        s[t] += add;
        __syncthreads();
    }
    Hb[t] = (s[t] - v) + H[blk * 256 + t];   // bucket base + tile offset
    c2[t] = 0;
    __syncthreads();
    int i0 = blk * TILE;
#pragma unroll
    for (int k = 0; k < TILE / 256; ++k) {
        int i = i0 + k * 256 + t;
        if (i < E) {
            int sv = src[i], d = dst[i];
            int b = d >> 8;
            unsigned rec = ((unsigned)(d & 255) << 16) | (unsigned)sv;
            int pos = Hb[b] + atomicAdd(&c2[b], 1);
            tmp[pos] = rec;
        }
    }
}

// ---- per-bucket CSR finalize: rows padded to x16, packed row_ptr ----
// pbase = align8(base) + b*4096 (per-bucket padding <= 256*15+7 < 4096),
// 16B-aligned row starts. row_ptr[node] = start | (pdeg/16)<<22.
#define COLCAP 8192
__global__ __launch_bounds__(256) void k_binB(const unsigned* __restrict__ tmp,
                                              const int* __restrict__ btot, int nb,
                                              int n, int E, int* __restrict__ row_ptr,
                                              float* __restrict__ inv,
                                              unsigned short* __restrict__ col) {
    __shared__ int dcnt[256], s[256], cur[256];
    __shared__ unsigned short colbuf[COLCAP];
    __shared__ int baseS;
    int t = threadIdx.x, b = blockIdx.x;
    int v = (t < nb) ? btot[t] : 0;
    s[t] = v;
    __syncthreads();
    for (int off = 1; off < 256; off <<= 1) {
        int add = (t >= off) ? s[t - off] : 0;
        __syncthreads();
        s[t] += add;
        __syncthreads();
    }
    if (t == b) baseS = s[t] - v;
    dcnt[t] = 0;
    __syncthreads();
    int base = baseS;
    int pbase = ((base + 7) & ~7) + b * 4096;
    int cntE = btot[b];
    int node0 = b << 8;
    int nn = min(256, n - node0);
    for (int i = t; i < cntE; i += 256) atomicAdd(&dcnt[tmp[base + i] >> 16], 1);
    __syncthreads();
    int deg = dcnt[t];
    int pdeg = (deg + 15) & ~15;
    s[t] = pdeg;
    __syncthreads();
    for (int off = 1; off < 256; off <<= 1) {
        int add = (t >= off) ? s[t - off] : 0;
        __syncthreads();
        s[t] += add;
        __syncthreads();
    }
    int pexcl = s[t] - pdeg;
    int ptot = s[255];
    if (t < nn) {
        row_ptr[node0 + t] = (pbase + pexcl) | ((pdeg >> 4) << 22);
        inv[node0 + t] = rsqrtf((float)(deg + 1));
    }
    if (b == 0 && t == 0) inv[n] = 0.f;   // sentinel weight
    cur[t] = pexcl;
    __syncthreads();
    for (int i = t; i < cntE; i += 256) {
        unsigned r = tmp[base + i];
        int pos = atomicAdd(&cur[r >> 16], 1);
        unsigned short vv = (unsigned short)(r & 0xFFFFu);
        if (pos < COLCAP) colbuf[pos] = vv;
        else col[pbase + pos] = vv;   // overflow fallback
    }
    // sentinel tail fill (disjoint from scatter range -> no barrier needed)
    if (t < nn) {
        int p1 = pexcl + pdeg;
        for (int p = pexcl + deg; p < p1; ++p) {
            if (p < COLCAP) colbuf[p] = (unsigned short)n;
            else col[pbase + p] = (unsigned short)n;
        }
    }
    __syncthreads();
    int lim = min(ptot, COLCAP);
    for (int i = t; i < lim; i += 256) col[pbase + i] = colbuf[i];
}

__device__ __forceinline__ void unpack8(const uint4& q, float* f) {
    float2 f0 = __half22float2(*(const __half2*)&q.x);
    float2 f1 = __half22float2(*(const __half2*)&q.y);
    float2 f2 = __half22float2(*(const __half2*)&q.z);
    float2 f3 = __half22float2(*(const __half2*)&q.w);
    f[0] = f0.x; f[1] = f0.y; f[2] = f1.x; f[3] = f1.y;
    f[4] = f2.x; f[5] = f2.y; f[6] = f3.x; f[7] = f3.y;
}
__device__ __forceinline__ void decode8(const uint4& cv, int* c) {
    c[0] = cv.x & 0xFFFF; c[1] = cv.x >> 16;
    c[2] = cv.y & 0xFFFF; c[3] = cv.y >> 16;
    c[4] = cv.z & 0xFFFF; c[5] = cv.z >> 16;
    c[6] = cv.w & 0xFFFF; c[7] = cv.w >> 16;
}

// ---- agg layer 1 (inv[src]-weighted) + fused W2 GEMM -> P2 (fp16) ----
// Phase A: 8 nodes/wave, 8 lanes x 8 halfs (uint4); rows padded to x16:
// per iter 2 col uint4 + 16 inv + 16 gathers issued straight-line (34
// outstanding), then 16 FMA groups. Phase B: 32 nodes x 8 col-octets.
__global__ __launch_bounds__(256) void k_aggF1(const __half* __restrict__ Ph, const float* __restrict__ inv,
                                               const int* __restrict__ row_ptr,
                                               const unsigned short* __restrict__ col,
                                               const float* __restrict__ bias,
                                               const float* __restrict__ W2,
                                               __half* __restrict__ P2, int n) {
    __shared__ float W2s[FDIM * FDIM];
    __shared__ float rbuf[32][FDIM + 1];
    int t0 = threadIdx.x;
    for (int i = t0; i < FDIM * FDIM; i += 256) W2s[i] = W2[i];
    // zero sentinel row n of P2 for aggF2
    if (blockIdx.x == 0 && t0 < 8)
        ((uint4*)P2)[(size_t)n * 8 + t0] = make_uint4(0, 0, 0, 0);
    int lane = t0 & 63;
    int sub = lane >> 3;      // node-in-wave 0..7
    int fl = lane & 7;        // feature octet 0..7
    int wid = t0 >> 6;
    int nl = wid * 8 + sub;   // local node 0..31
    int node = blockIdx.x * 32 + nl;
    bool alive = node < n;
    int nodeC = alive ? node : (n - 1);
    float iv = inv[nodeC];
    const uint4* Pq = (const uint4*)Ph;
    uint4 selfq = Pq[(size_t)nodeC * 8 + fl];
    float a[8], f[8];
    unpack8(selfq, f);
#pragma unroll
    for (int i = 0; i < 8; ++i) a[i] = iv * f[i];   // self term: inv[d]*h[d]
    int v = row_ptr[nodeC];
    int s = v & 0x3FFFFF;
    int e = alive ? s + ((v >> 22) << 4) : s;
    for (int j = s; j < e; j += 16) {
        uint4 cv0 = *(const uint4*)(col + j);       // 8 cols
        uint4 cv1 = *(const uint4*)(col + j + 8);   // 8 cols
        int c[16];
        decode8(cv0, c);
        decode8(cv1, c + 8);
        float wk[16];
#pragma unroll
        for (int k = 0; k < 16; ++k) wk[k] = inv[c[k]];   // inv[n]=0 kills pads
        uint4 q[16];
#pragma unroll
        for (int k = 0; k < 16; ++k) q[k] = Pq[(size_t)c[k] * 8 + fl];
#pragma unroll
        for (int k = 0; k < 16; ++k) {
            unpack8(q[k], f);
#pragma unroll
            for (int i = 0; i < 8; ++i) a[i] = fmaf(wk[k], f[i], a[i]);
        }
    }
    float4 bb0 = ((const float4*)bias)[fl * 2];
    float4 bb1 = ((const float4*)bias)[fl * 2 + 1];
    float bbv[8] = {bb0.x, bb0.y, bb0.z, bb0.w, bb1.x, bb1.y, bb1.z, bb1.w};
#pragma unroll
    for (int i = 0; i < 8; ++i)
        rbuf[nl][fl * 8 + i] = fmaxf(fmaf(iv, a[i], bbv[i]), 0.f);
    __syncthreads();   // covers W2s load too
    // Phase B: 256 threads = 32 nodes x 8 col-octets
    int nl2 = t0 >> 3;
    int cg = t0 & 7;
    int node2 = blockIdx.x * 32 + nl2;
    const float* rr = rbuf[nl2];
    float o[8];
#pragma unroll
    for (int i = 0; i < 8; ++i) o[i] = 0.f;
#pragma unroll
    for (int i = 0; i < FDIM; ++i) {
        float xk = rr[i];
        const float* wv = &W2s[i * FDIM + cg * 8];
#pragma unroll
        for (int c = 0; c < 8; ++c) o[c] = fmaf(xk, wv[c], o[c]);
    }
    if (node2 < n) {
        float iv2 = inv[node2];
        unsigned u[4];
#pragma unroll
        for (int i = 0; i < 4; ++i) {
            __half2 hp = __floats2half2_rn(o[2 * i] * iv2, o[2 * i + 1] * iv2);
            u[i] = *(unsigned*)&hp;
        }
        ((uint4*)P2)[(size_t)node2 * 8 + cg] = make_uint4(u[0], u[1], u[2], u[3]);
    }
}

// ---- agg layer 2 + fused classifier (P2 pre-scaled -> weight-free) ----
// Padded x16 rows + zeroed sentinel P2 row -> unconditional adds, no masks;
// per iter 2 col uint4 + 16 gathers straight-line (18 outstanding).
__global__ __launch_bounds__(256) void k_aggF2(const __half* __restrict__ Ph, const float* __restrict__ inv,
                                               const int* __restrict__ row_ptr,
                                               const unsigned short* __restrict__ col,
                                               const float* __restrict__ bias,
                                               const float* __restrict__ Wc, const float* __restrict__ bc,
                                               float* __restrict__ out, int n) {
    __shared__ float WcT[NCLS * FDIM];   // transposed: WcT[c*64+f]
    int t0 = threadIdx.x;
    for (int i = t0; i < FDIM * NCLS; i += 256) {
        int c = i & 15, ff = i >> 4;
        WcT[c * FDIM + ff] = Wc[i];
    }
    __syncthreads();
    int lane = t0 & 63;
    int sub = lane >> 3;
    int fl = lane & 7;
    int wid = t0 >> 6;
    int node = blockIdx.x * 32 + wid * 8 + sub;
    bool alive = node < n;
    int nodeC = alive ? node : (n - 1);
    float iv = inv[nodeC];
    const uint4* Pq = (const uint4*)Ph;
    uint4 selfq = Pq[(size_t)nodeC * 8 + fl];
    float a[8], f[8];
    unpack8(selfq, a);
    int v = row_ptr[nodeC];
    int s = v & 0x3FFFFF;
    int e = alive ? s + ((v >> 22) << 4) : s;
    for (int j = s; j < e; j += 16) {
        uint4 cv0 = *(const uint4*)(col + j);
        uint4 cv1 = *(const uint4*)(col + j + 8);
        int c[16];
        decode8(cv0, c);
        decode8(cv1, c + 8);
        uint4 q[16];
#pragma unroll
        for (int k = 0; k < 16; ++k) q[k] = Pq[(size_t)c[k] * 8 + fl];
#pragma unroll
        for (int k = 0; k < 16; ++k) {
            unpack8(q[k], f);
#pragma unroll
            for (int i = 0; i < 8; ++i) a[i] += f[i];   // sentinel row = zeros
        }
    }
    float4 bb0 = ((const float4*)bias)[fl * 2];
    float4 bb1 = ((const float4*)bias)[fl * 2 + 1];
    float bbv[8] = {bb0.x, bb0.y, bb0.z, bb0.w, bb1.x, bb1.y, bb1.z, bb1.w};
    float r[8];
#pragma unroll
    for (int i = 0; i < 8; ++i) r[i] = fmaxf(fmaf(iv, a[i], bbv[i]), 0.f);
    float part[NCLS];
#pragma unroll
    for (int c = 0; c < NCLS; ++c) {
        float4 wv0 = ((const float4*)(WcT + c * FDIM))[fl * 2];
        float4 wv1 = ((const float4*)(WcT + c * FDIM))[fl * 2 + 1];
        part[c] = r[0] * wv0.x;
        part[c] = fmaf(r[1], wv0.y, part[c]);
        part[c] = fmaf(r[2], wv0.z, part[c]);
        part[c] = fmaf(r[3], wv0.w, part[c]);
        part[c] = fmaf(r[4], wv1.x, part[c]);
        part[c] = fmaf(r[5], wv1.y, part[c]);
        part[c] = fmaf(r[6], wv1.z, part[c]);
        part[c] = fmaf(r[7], wv1.w, part[c]);
    }
#pragma unroll
    for (int m = 1; m < 8; m <<= 1) {
#pragma unroll
        for (int c = 0; c < NCLS; ++c) part[c] += __shfl_xor(part[c], m, 64);
    }
    if (alive && fl < 4) {
        float4 bb2 = ((const float4*)bc)[fl];
        float4 o = make_float4(part[fl * 4 + 0] + bb2.x, part[fl * 4 + 1] + bb2.y,
                               part[fl * 4 + 2] + bb2.z, part[fl * 4 + 3] + bb2.w);
        ((float4*)out)[(size_t)node * 4 + fl] = o;
    }
}

static inline size_t align256(size_t x) { return (x + 255) & ~(size_t)255; }

extern "C" void kernel_launch(void* const* d_in, const int* in_sizes, int n_in,
                              void* d_out, int out_size, void* d_ws, size_t ws_size,
                              hipStream_t stream) {
    const float* x  = (const float*)d_in[0];
    const int*   ei = (const int*)d_in[1];
    const float* W1 = (const float*)d_in[2];
    const float* b1 = (const float*)d_in[3];
    const float* W2 = (const float*)d_in[4];
    const float* b2 = (const float*)d_in[5];
    const float* Wc = (const float*)d_in[6];
    const float* bc = (const float*)d_in[7];
    float* out = (float*)d_out;

    const int n = in_sizes[0] / FDIM;   // 50000
    const int E = in_sizes[1] / 2;      // 800000
    const int* src = ei;
    const int* dst = ei + E;

    const int nb = (n + 255) >> 8;            // 196 buckets
    const int nblk = (E + TILE - 1) / TILE;   // 391 tiles

    // workspace carve-up (inv/P1/P2 have +1 sentinel entry/row; col padded x16)
    char* w = (char*)d_ws;
    size_t off = 0;
    int* H = (int*)(w + off);        off = align256(off + (size_t)nblk * 256 * 4);
    int* btot = (int*)(w + off);     off = align256(off + 256 * 4);
    int* row_ptr = (int*)(w + off);  off = align256(off + (size_t)(n + 1) * 4);
    float* inv = (float*)(w + off);  off = align256(off + (size_t)(n + 1) * 4);
    unsigned* tmp = (unsigned*)(w + off);             off = align256(off + (size_t)E * 4);
    unsigned short* col = (unsigned short*)(w + off); off = align256(off + ((size_t)E + (size_t)nb * 4096 + 128) * 2);
    __half* P1 = (__half*)(w + off); off = align256(off + (size_t)(n + 1) * FDIM * 2);
    __half* P2 = (__half*)(w + off); off = align256(off + (size_t)(n + 1) * FDIM * 2);
    (void)ws_size;

    const int nbG = (n * 4 + 255) / 256;
    const int nbA = (n + 31) / 32;     // 32 nodes per block

    // CSR build + fused layer-1 GEMM riding along
    k_histgemm<<<nblk + nbG, 256, 0, stream>>>(dst, E, H, nblk, x, W1, P1, n);
    k_scanH<<<nb, 512, 0, stream>>>(H, nblk, btot);
    k_scatA<<<nblk, 256, 0, stream>>>(src, dst, E, H, btot, nb, tmp);
    k_binB<<<nb, 256, 0, stream>>>(tmp, btot, nb, n, E, row_ptr, inv, col);

    // layer 1 agg (inv[src]-weighted) + fused layer 2 GEMM -> P2 (pre-scaled)
    k_aggF1<<<nbA, 256, 0, stream>>>(P1, inv, row_ptr, col, b1, W2, P2, n);
    // layer 2 agg + fused classifier
    k_aggF2<<<nbA, 256, 0, stream>>>(P2, inv, row_ptr, col, b2, Wc, bc, out, n);
}